// Round 7
// baseline (809.610 us; speedup 1.0000x reference)
//
#include <hip/hip_runtime.h>
#include <hip/hip_cooperative_groups.h>

namespace cg = cooperative_groups;

#define NN 4096
#define KK 1024
#define NWG 256
#define TPB 1024
#define NWAVE 16
#define RPW 16
#define LAMf 100.0f
#define LOGMU (-8.317766166719343f)
#define THRESHf 0.1f
#define NITERS 100
#define FBIG 3.402823466e+38f

struct SweepShared {
  float2 sBpn[NN];   // (lam*other_p, lam*other_n)  32 KB
  int    sT[NN];     // targets                     16 KB
  float  sErr[2][RPW];
  float  sFlat[64];
  float  sScal[8];
};

__device__ __forceinline__ void elem_accum(float d, int tj, int ti,
    float Bp, float Bn, float Ap, float An, float s_p, float s_n,
    float& accp, float& accn)
{
  const bool pos = (tj == ti);
  const float crp = d + (d > 0.8f ? 1.0f : 0.0f);          // pos raw cost
  const float crn = (d < 0.4f ? 2.0f : 1.0f) - d;          // neg raw cost
  const float cr = pos ? crp : crn;
  const float A  = pos ? Ap : An;
  const float B  = pos ? Bp : Bn;
  const float ss = pos ? s_p : s_n;
  const float e  = __expf(A + B - ss * cr);
  accp += pos ? e : 0.0f;
  accn += pos ? 0.0f : e;
}

// One half-iteration: LSE over rows of dist for "own" side, using staged "other" side.
// Phase R: own=u, other=v.  Phase C (symmetric dist): own=v, other=u.
template<bool DO_ERR>
__device__ __forceinline__ void sweep_pass(
    SweepShared& sh,
    const float* __restrict__ dist, const int* __restrict__ targets,
    float* __restrict__ ownP, float* __restrict__ ownN,
    const float* __restrict__ othP, const float* __restrict__ othN,
    float s_p, float s_n, float lo_p, float lo_n,
    bool actP, bool actN, float* __restrict__ err_part,
    int wg, int tid, int lane, int wv)
{
  __syncthreads();
  #pragma unroll
  for (int c = 0; c < NN / TPB; ++c) {
    const int j = tid + TPB * c;
    sh.sBpn[j] = make_float2(LAMf * othP[j], LAMf * othN[j]);
  }
  __syncthreads();

  const int i = wg * RPW + wv;          // this wave's row (== col, dist symmetric)
  const int ti = targets[i];
  const float uop = ownP[i];
  const float uon = ownN[i];
  const float Ap = LAMf * uop + s_p * lo_p;
  const float An = LAMf * uon + s_n * lo_n;
  const float* __restrict__ drow = dist + (size_t)i * NN;
  float accp = 0.0f, accn = 0.0f;
  #pragma unroll 4
  for (int c = 0; c < 16; ++c) {
    const int j0 = lane * 4 + 256 * c;
    const float4 d4 = *(const float4*)(drow + j0);
    const int4   t4 = *(const int4*)(sh.sT + j0);
    const float4 q0 = *(const float4*)(&sh.sBpn[j0]);
    const float4 q1 = *(const float4*)(&sh.sBpn[j0 + 2]);
    elem_accum(d4.x, t4.x, ti, q0.x, q0.y, Ap, An, s_p, s_n, accp, accn);
    elem_accum(d4.y, t4.y, ti, q0.z, q0.w, Ap, An, s_p, s_n, accp, accn);
    elem_accum(d4.z, t4.z, ti, q1.x, q1.y, Ap, An, s_p, s_n, accp, accn);
    elem_accum(d4.w, t4.w, ti, q1.z, q1.w, Ap, An, s_p, s_n, accp, accn);
  }
  #pragma unroll
  for (int off = 32; off; off >>= 1) {
    accp += __shfl_xor(accp, off, 64);
    accn += __shfl_xor(accn, off, 64);
  }
  if (lane == 0) {
    const float unp = (LOGMU - logf(accp + 1e-6f)) / LAMf + uop;
    const float unn = (LOGMU - logf(accn + 1e-6f)) / LAMf + uon;
    if (actP) ownP[i] = unp;
    if (actN) ownN[i] = unn;
    if (DO_ERR) {
      sh.sErr[0][wv] = fabsf(unp - uop);
      sh.sErr[1][wv] = fabsf(unn - uon);
    }
  }
  if (DO_ERR) {
    __syncthreads();
    if (tid < 2) {
      const bool act = tid ? actN : actP;
      if (act) {
        float e = 0.0f;
        #pragma unroll
        for (int r = 0; r < RPW; ++r) e += sh.sErr[tid][r];
        err_part[wg * 2 + tid] = e;
      }
    }
  }
}

__global__ void __launch_bounds__(TPB, 1) sinkhorn_all(
    const float* __restrict__ dist, const int* __restrict__ targets,
    float* __restrict__ u_p, float* __restrict__ u_n,
    float* __restrict__ v_p, float* __restrict__ v_n,
    float* __restrict__ mm_part, float* __restrict__ err_part,
    float* __restrict__ loss_part, float* __restrict__ out)
{
  cg::grid_group grid = cg::this_grid();
  __shared__ SweepShared sh;
  const int tid = threadIdx.x;
  const int wg = blockIdx.x;
  const int lane = tid & 63;
  const int wv = tid >> 6;

  #pragma unroll
  for (int c = 0; c < NN / TPB; ++c) {
    const int j = tid + TPB * c;
    sh.sT[j] = targets[j];
  }
  if (tid < RPW) {
    const int i = wg * RPW + tid;
    u_p[i] = 0.0f; u_n[i] = 0.0f; v_p[i] = 0.0f; v_n[i] = 0.0f;
  }
  __syncthreads();

  // ---- global min/max of raw cost matrices (for _minmax_norm constants) ----
  {
    const int i = wg * RPW + wv;
    const int ti = targets[i];
    const float* drow = dist + (size_t)i * NN;
    float mnp = FBIG, mxp = -FBIG, mnn = FBIG, mxn = -FBIG;
    #pragma unroll 4
    for (int c = 0; c < 16; ++c) {
      const int j0 = lane * 4 + 256 * c;
      const float4 d4 = *(const float4*)(drow + j0);
      const int4   t4 = *(const int4*)(sh.sT + j0);
      const float dd[4] = {d4.x, d4.y, d4.z, d4.w};
      const int   tt[4] = {t4.x, t4.y, t4.z, t4.w};
      #pragma unroll
      for (int q = 0; q < 4; ++q) {
        const bool pos = (tt[q] == ti);
        const float d = dd[q];
        const float crp = pos ? (d + (d > 0.8f ? 1.0f : 0.0f)) : 30.0f;
        const float crn = pos ? 30.0f : ((d < 0.4f ? 2.0f : 1.0f) - d);
        mnp = fminf(mnp, crp); mxp = fmaxf(mxp, crp);
        mnn = fminf(mnn, crn); mxn = fmaxf(mxn, crn);
      }
    }
    #pragma unroll
    for (int off = 32; off; off >>= 1) {
      mnp = fminf(mnp, __shfl_xor(mnp, off, 64));
      mxp = fmaxf(mxp, __shfl_xor(mxp, off, 64));
      mnn = fminf(mnn, __shfl_xor(mnn, off, 64));
      mxn = fmaxf(mxn, __shfl_xor(mxn, off, 64));
    }
    if (lane == 0) {
      sh.sFlat[wv * 4 + 0] = mnp; sh.sFlat[wv * 4 + 1] = mxp;
      sh.sFlat[wv * 4 + 2] = mnn; sh.sFlat[wv * 4 + 3] = mxn;
    }
    __syncthreads();
    if (tid == 0) {
      float a = FBIG, b = -FBIG, c2 = FBIG, d2 = -FBIG;
      #pragma unroll
      for (int w = 0; w < NWAVE; ++w) {
        a = fminf(a, sh.sFlat[w*4+0]); b = fmaxf(b, sh.sFlat[w*4+1]);
        c2 = fminf(c2, sh.sFlat[w*4+2]); d2 = fmaxf(d2, sh.sFlat[w*4+3]);
      }
      mm_part[wg*4+0] = a; mm_part[wg*4+1] = b;
      mm_part[wg*4+2] = c2; mm_part[wg*4+3] = d2;
    }
  }
  grid.sync();
  if (tid == 0) {   // every WG redundantly reduces (identical result => uniform)
    float a = FBIG, b = -FBIG, c2 = FBIG, d2 = -FBIG;
    for (int w = 0; w < NWG; ++w) {
      a = fminf(a, mm_part[w*4+0]); b = fmaxf(b, mm_part[w*4+1]);
      c2 = fminf(c2, mm_part[w*4+2]); d2 = fmaxf(d2, mm_part[w*4+3]);
    }
    sh.sScal[0] = a; sh.sScal[1] = b; sh.sScal[2] = c2; sh.sScal[3] = d2;
  }
  __syncthreads();
  const float lo_p = sh.sScal[0], hi_p = sh.sScal[1];
  const float lo_n = sh.sScal[2], hi_n = sh.sScal[3];
  const float s_p = LAMf / (hi_p - lo_p);
  const float s_n = LAMf / (hi_n - lo_n);

  // ---- Sinkhorn iterations (both problems fused) ----
  bool done_p = false, done_n = false;
  for (int it = 0; it < NITERS; ++it) {
    sweep_pass<true >(sh, dist, targets, u_p, u_n, v_p, v_n,
                      s_p, s_n, lo_p, lo_n, !done_p, !done_n, err_part, wg, tid, lane, wv);
    grid.sync();
    sweep_pass<false>(sh, dist, targets, v_p, v_n, u_p, u_n,
                      s_p, s_n, lo_p, lo_n, !done_p, !done_n, err_part, wg, tid, lane, wv);
    grid.sync();
    {
      float ep = 0.0f, en = 0.0f;
      if (tid < NWG) { ep = err_part[2*tid]; en = err_part[2*tid+1]; }
      #pragma unroll
      for (int off = 32; off; off >>= 1) {
        ep += __shfl_xor(ep, off, 64);
        en += __shfl_xor(en, off, 64);
      }
      if (lane == 0) { sh.sFlat[wv*2] = ep; sh.sFlat[wv*2+1] = en; }
      __syncthreads();
      if (tid == 0) {
        float a = 0.0f, b = 0.0f;
        #pragma unroll
        for (int w = 0; w < NWAVE; ++w) { a += sh.sFlat[w*2]; b += sh.sFlat[w*2+1]; }
        sh.sScal[4] = a; sh.sScal[5] = b;
      }
      __syncthreads();
      if (sh.sScal[4] < THRESHf) done_p = true;
      if (sh.sScal[5] < THRESHf) done_n = true;
    }
    if (done_p && done_n) break;
  }

  // ---- loss = sum(pi_pos*edge_pos) + sum(pi_neg*edge_neg) ----
  __syncthreads();
  #pragma unroll
  for (int c = 0; c < NN / TPB; ++c) {
    const int j = tid + TPB * c;
    sh.sBpn[j] = make_float2(LAMf * v_p[j], LAMf * v_n[j]);
  }
  __syncthreads();
  {
    const int i = wg * RPW + wv;
    const int ti = targets[i];
    const float Ap = LAMf * u_p[i] + s_p * lo_p;
    const float An = LAMf * u_n[i] + s_n * lo_n;
    const float* drow = dist + (size_t)i * NN;
    float lacc = 0.0f;
    #pragma unroll 4
    for (int c = 0; c < 16; ++c) {
      const int j0 = lane * 4 + 256 * c;
      const float4 d4 = *(const float4*)(drow + j0);
      const int4   t4 = *(const int4*)(sh.sT + j0);
      const float4 q0 = *(const float4*)(&sh.sBpn[j0]);
      const float4 q1 = *(const float4*)(&sh.sBpn[j0 + 2]);
      const float dd[4] = {d4.x, d4.y, d4.z, d4.w};
      const int   tt[4] = {t4.x, t4.y, t4.z, t4.w};
      const float bp[4] = {q0.x, q0.z, q1.x, q1.z};
      const float bn[4] = {q0.y, q0.w, q1.y, q1.w};
      #pragma unroll
      for (int q = 0; q < 4; ++q) {
        const bool pos = (tt[q] == ti);
        const float d = dd[q];
        const float crp = d + (d > 0.8f ? 1.0f : 0.0f);
        const float crn = (d < 0.4f ? 2.0f : 1.0f) - d;
        const float cr = pos ? crp : crn;
        const float A = pos ? Ap : An;
        const float B = pos ? bp[q] : bn[q];
        const float ss = pos ? s_p : s_n;
        const float pi = __expf(A + B - ss * cr);
        const float edge = pos ? fmaxf(0.8f - d, 0.0f) : fmaxf(d - 0.4f, 0.0f);
        lacc += pi * edge;   // cross-class terms are ~1e-40*(-1e7): negligible, skipped
      }
    }
    #pragma unroll
    for (int off = 32; off; off >>= 1) lacc += __shfl_xor(lacc, off, 64);
    if (lane == 0) sh.sFlat[wv] = lacc;
    __syncthreads();
    if (tid == 0) {
      float s = 0.0f;
      #pragma unroll
      for (int w = 0; w < NWAVE; ++w) s += sh.sFlat[w];
      loss_part[wg] = s;
    }
  }
  grid.sync();
  if (wg == 0 && tid == 0) {
    float s = 0.0f;
    for (int w = 0; w < NWG; ++w) s += loss_part[w];
    out[0] = s;   // SCALE = 1.0
  }
}

// ---- row norms: invn[i] = 1/max(||E_i||, 1e-12) ----
__global__ void __launch_bounds__(256) rownorm_k(const float* __restrict__ E,
                                                 float* __restrict__ invn)
{
  __shared__ float red[4];
  const int i = blockIdx.x;
  const int tid = threadIdx.x;
  const float4 v4 = ((const float4*)(E + (size_t)i * KK))[tid];
  float s = v4.x*v4.x + v4.y*v4.y + v4.z*v4.z + v4.w*v4.w;
  #pragma unroll
  for (int off = 32; off; off >>= 1) s += __shfl_xor(s, off, 64);
  if ((tid & 63) == 0) red[tid >> 6] = s;
  __syncthreads();
  if (tid == 0) {
    const float t = red[0] + red[1] + red[2] + red[3];
    invn[i] = 1.0f / fmaxf(sqrtf(t), 1e-12f);
  }
}

// ---- dist = (E*invn) @ (E*invn)^T, fp32 LDS-tiled SGEMM, 64x64 tile ----
#define GT 64
__global__ void __launch_bounds__(256) gemm_dist_k(const float* __restrict__ E,
                                                   const float* __restrict__ invn,
                                                   float* __restrict__ dist)
{
  __shared__ float As[16][68];
  __shared__ float Bs[16][68];
  const int tid = threadIdx.x;
  const int tx = tid & 15, ty = tid >> 4;
  const int row0 = blockIdx.y * GT, col0 = blockIdx.x * GT;
  float acc[4][4];
  #pragma unroll
  for (int a = 0; a < 4; ++a)
    #pragma unroll
    for (int b = 0; b < 4; ++b) acc[a][b] = 0.0f;

  for (int k0 = 0; k0 < KK; k0 += 16) {
    #pragma unroll
    for (int s = 0; s < 4; ++s) {
      const int e = tid + 256 * s;
      const int r = e >> 4, k = e & 15;
      As[k][r] = E[(size_t)(row0 + r) * KK + k0 + k];
      Bs[k][r] = E[(size_t)(col0 + r) * KK + k0 + k];
    }
    __syncthreads();
    #pragma unroll
    for (int k = 0; k < 16; ++k) {
      const float4 a4 = *(const float4*)&As[k][ty * 4];
      const float4 b4 = *(const float4*)&Bs[k][tx * 4];
      const float av[4] = {a4.x, a4.y, a4.z, a4.w};
      const float bv[4] = {b4.x, b4.y, b4.z, b4.w};
      #pragma unroll
      for (int a = 0; a < 4; ++a)
        #pragma unroll
        for (int b = 0; b < 4; ++b) acc[a][b] = fmaf(av[a], bv[b], acc[a][b]);
    }
    __syncthreads();
  }
  float ai[4], bj[4];
  #pragma unroll
  for (int a = 0; a < 4; ++a) ai[a] = invn[row0 + ty * 4 + a];
  #pragma unroll
  for (int b = 0; b < 4; ++b) bj[b] = invn[col0 + tx * 4 + b];
  #pragma unroll
  for (int a = 0; a < 4; ++a) {
    const size_t ro = (size_t)(row0 + ty * 4 + a) * NN + col0 + tx * 4;
    float4 o;
    o.x = acc[a][0] * ai[a] * bj[0];
    o.y = acc[a][1] * ai[a] * bj[1];
    o.z = acc[a][2] * ai[a] * bj[2];
    o.w = acc[a][3] * ai[a] * bj[3];
    *(float4*)&dist[ro] = o;
  }
}

extern "C" void kernel_launch(void* const* d_in, const int* in_sizes, int n_in,
                              void* d_out, int out_size, void* d_ws, size_t ws_size,
                              hipStream_t stream) {
  (void)in_sizes; (void)n_in; (void)out_size; (void)ws_size;
  const float* E = (const float*)d_in[0];
  const int* T = (const int*)d_in[1];
  float* out = (float*)d_out;
  float* ws = (float*)d_ws;

  float* dist      = ws;                          // 4096*4096
  float* invn      = ws + (size_t)NN * NN;        // 4096
  float* u_p       = invn + NN;
  float* u_n       = u_p + NN;
  float* v_p       = u_n + NN;
  float* v_n       = v_p + NN;
  float* mm_part   = v_n + NN;                    // NWG*4
  float* err_part  = mm_part + NWG * 4;           // NWG*2
  float* loss_part = err_part + NWG * 2;          // NWG

  rownorm_k<<<NN, 256, 0, stream>>>(E, invn);
  dim3 g(NN / GT, NN / GT);
  gemm_dist_k<<<g, 256, 0, stream>>>(E, invn, dist);

  void* args[] = { (void*)&dist, (void*)&T, (void*)&u_p, (void*)&u_n,
                   (void*)&v_p, (void*)&v_n, (void*)&mm_part,
                   (void*)&err_part, (void*)&loss_part, (void*)&out };
  hipLaunchCooperativeKernel(sinkhorn_all, dim3(NWG), dim3(TPB), args, 0u, stream);
}

// Round 9
// 403.597 us; speedup vs baseline: 2.0060x; 2.0060x over previous
//
#include <hip/hip_runtime.h>
#include <hip/hip_bf16.h>
#include <hip/hip_cooperative_groups.h>

namespace cg = cooperative_groups;

#define NN 4096
#define KK 1024
#define NWG 256
#define TPB 1024
#define NWAVE 16
#define RPW 16
#define LAMf 100.0f
#define LOGMU (-8.317766166719343f)
#define THRESHf 0.1f
#define NITERS 100
#define FBIG 3.402823466e+38f

typedef __attribute__((ext_vector_type(8))) short bf16x8;
typedef __attribute__((ext_vector_type(4))) float f32x4;

__device__ __forceinline__ float bflo(unsigned u) { return __uint_as_float(u << 16); }
__device__ __forceinline__ float bfhi(unsigned u) { return __uint_as_float(u & 0xffff0000u); }
__device__ __forceinline__ unsigned short f2bf(float x) {   // RNE f32->bf16 (finite inputs)
  unsigned u = __float_as_uint(x);
  return (unsigned short)((u + 0x7fffu + ((u >> 16) & 1u)) >> 16);
}

struct SweepShared {
  float2 sBpn[NN];   // (lam*other_p, lam*other_n)  32 KB
  int    sT[NN];     // targets                     16 KB
  float  sErr[2][RPW];
  float  sFlat[64];
  float  sScal[8];
};

__device__ __forceinline__ void elem_accum(float d, int tj, int ti,
    float Bp, float Bn, float Ap, float An, float s_p, float s_n,
    float& accp, float& accn)
{
  const bool pos = (tj == ti);
  const float crp = d + (d > 0.8f ? 1.0f : 0.0f);          // pos raw cost
  const float crn = (d < 0.4f ? 2.0f : 1.0f) - d;          // neg raw cost
  const float cr = pos ? crp : crn;
  const float A  = pos ? Ap : An;
  const float B  = pos ? Bp : Bn;
  const float ss = pos ? s_p : s_n;
  const float e  = __expf(A + B - ss * cr);
  accp += pos ? e : 0.0f;
  accn += pos ? 0.0f : e;
}

__device__ __forceinline__ void unp8(uint4 dv, float* d) {
  d[0] = bflo(dv.x); d[1] = bfhi(dv.x); d[2] = bflo(dv.y); d[3] = bfhi(dv.y);
  d[4] = bflo(dv.z); d[5] = bfhi(dv.z); d[6] = bflo(dv.w); d[7] = bfhi(dv.w);
}

// One half-iteration: LSE over rows of dist for "own" side, using staged "other" side.
// dist is symmetric, so both phases are row scans.
template<bool DO_ERR>
__device__ __forceinline__ void sweep_pass(
    SweepShared& sh,
    const unsigned short* __restrict__ dist, const int* __restrict__ targets,
    float* __restrict__ ownP, float* __restrict__ ownN,
    const float* __restrict__ othP, const float* __restrict__ othN,
    float s_p, float s_n, float lo_p, float lo_n,
    bool actP, bool actN, float* __restrict__ err_part,
    int wg, int tid, int lane, int wv)
{
  __syncthreads();
  #pragma unroll
  for (int c = 0; c < NN / TPB; ++c) {
    const int j = tid + TPB * c;
    sh.sBpn[j] = make_float2(LAMf * othP[j], LAMf * othN[j]);
  }
  __syncthreads();

  const int i = wg * RPW + wv;          // this wave's row (== col, dist symmetric)
  const int ti = targets[i];
  const float uop = ownP[i];
  const float uon = ownN[i];
  const float Ap = LAMf * uop + s_p * lo_p;
  const float An = LAMf * uon + s_n * lo_n;
  const unsigned short* __restrict__ drow = dist + (size_t)i * NN;
  float accp = 0.0f, accn = 0.0f;
  #pragma unroll 2
  for (int c = 0; c < 8; ++c) {
    const int j0 = lane * 8 + 512 * c;
    const uint4 dv = *(const uint4*)(drow + j0);
    const int4 t0 = *(const int4*)(sh.sT + j0);
    const int4 t1 = *(const int4*)(sh.sT + j0 + 4);
    const float4 q0 = *(const float4*)(&sh.sBpn[j0]);
    const float4 q1 = *(const float4*)(&sh.sBpn[j0 + 2]);
    const float4 q2 = *(const float4*)(&sh.sBpn[j0 + 4]);
    const float4 q3 = *(const float4*)(&sh.sBpn[j0 + 6]);
    float d8[8]; unp8(dv, d8);
    elem_accum(d8[0], t0.x, ti, q0.x, q0.y, Ap, An, s_p, s_n, accp, accn);
    elem_accum(d8[1], t0.y, ti, q0.z, q0.w, Ap, An, s_p, s_n, accp, accn);
    elem_accum(d8[2], t0.z, ti, q1.x, q1.y, Ap, An, s_p, s_n, accp, accn);
    elem_accum(d8[3], t0.w, ti, q1.z, q1.w, Ap, An, s_p, s_n, accp, accn);
    elem_accum(d8[4], t1.x, ti, q2.x, q2.y, Ap, An, s_p, s_n, accp, accn);
    elem_accum(d8[5], t1.y, ti, q2.z, q2.w, Ap, An, s_p, s_n, accp, accn);
    elem_accum(d8[6], t1.z, ti, q3.x, q3.y, Ap, An, s_p, s_n, accp, accn);
    elem_accum(d8[7], t1.w, ti, q3.z, q3.w, Ap, An, s_p, s_n, accp, accn);
  }
  #pragma unroll
  for (int off = 32; off; off >>= 1) {
    accp += __shfl_xor(accp, off, 64);
    accn += __shfl_xor(accn, off, 64);
  }
  if (lane == 0) {
    const float unp = (LOGMU - logf(accp + 1e-6f)) / LAMf + uop;
    const float unn = (LOGMU - logf(accn + 1e-6f)) / LAMf + uon;
    if (actP) ownP[i] = unp;
    if (actN) ownN[i] = unn;
    if (DO_ERR) {
      sh.sErr[0][wv] = fabsf(unp - uop);
      sh.sErr[1][wv] = fabsf(unn - uon);
    }
  }
  if (DO_ERR) {
    __syncthreads();
    if (tid < 2) {
      const bool act = tid ? actN : actP;
      if (act) {
        float e = 0.0f;
        #pragma unroll
        for (int r = 0; r < RPW; ++r) e += sh.sErr[tid][r];
        err_part[wg * 2 + tid] = e;
      }
    }
  }
}

__global__ void __launch_bounds__(TPB, 1) sinkhorn_all(
    const unsigned short* __restrict__ dist, const int* __restrict__ targets,
    float* __restrict__ u_p, float* __restrict__ u_n,
    float* __restrict__ v_p, float* __restrict__ v_n,
    float* __restrict__ mm_part, float* __restrict__ err_part,
    float* __restrict__ loss_part, float* __restrict__ out)
{
  cg::grid_group grid = cg::this_grid();
  __shared__ SweepShared sh;
  const int tid = threadIdx.x;
  const int wg = blockIdx.x;
  const int lane = tid & 63;
  const int wv = tid >> 6;

  #pragma unroll
  for (int c = 0; c < NN / TPB; ++c) {
    const int j = tid + TPB * c;
    sh.sT[j] = targets[j];
  }
  if (tid < RPW) {
    const int i = wg * RPW + tid;
    u_p[i] = 0.0f; u_n[i] = 0.0f; v_p[i] = 0.0f; v_n[i] = 0.0f;
  }
  __syncthreads();

  // ---- global min/max of raw cost matrices (for _minmax_norm constants) ----
  {
    const int i = wg * RPW + wv;
    const int ti = targets[i];
    const unsigned short* drow = dist + (size_t)i * NN;
    float mnp = FBIG, mxp = -FBIG, mnn = FBIG, mxn = -FBIG;
    #pragma unroll 2
    for (int c = 0; c < 8; ++c) {
      const int j0 = lane * 8 + 512 * c;
      const uint4 dv = *(const uint4*)(drow + j0);
      const int4 t0 = *(const int4*)(sh.sT + j0);
      const int4 t1 = *(const int4*)(sh.sT + j0 + 4);
      float d8[8]; unp8(dv, d8);
      const int tt[8] = {t0.x, t0.y, t0.z, t0.w, t1.x, t1.y, t1.z, t1.w};
      #pragma unroll
      for (int q = 0; q < 8; ++q) {
        const bool pos = (tt[q] == ti);
        const float d = d8[q];
        const float crp = pos ? (d + (d > 0.8f ? 1.0f : 0.0f)) : 30.0f;
        const float crn = pos ? 30.0f : ((d < 0.4f ? 2.0f : 1.0f) - d);
        mnp = fminf(mnp, crp); mxp = fmaxf(mxp, crp);
        mnn = fminf(mnn, crn); mxn = fmaxf(mxn, crn);
      }
    }
    #pragma unroll
    for (int off = 32; off; off >>= 1) {
      mnp = fminf(mnp, __shfl_xor(mnp, off, 64));
      mxp = fmaxf(mxp, __shfl_xor(mxp, off, 64));
      mnn = fminf(mnn, __shfl_xor(mnn, off, 64));
      mxn = fmaxf(mxn, __shfl_xor(mxn, off, 64));
    }
    if (lane == 0) {
      sh.sFlat[wv * 4 + 0] = mnp; sh.sFlat[wv * 4 + 1] = mxp;
      sh.sFlat[wv * 4 + 2] = mnn; sh.sFlat[wv * 4 + 3] = mxn;
    }
    __syncthreads();
    if (tid == 0) {
      float a = FBIG, b = -FBIG, c2 = FBIG, d2 = -FBIG;
      #pragma unroll
      for (int w = 0; w < NWAVE; ++w) {
        a = fminf(a, sh.sFlat[w*4+0]); b = fmaxf(b, sh.sFlat[w*4+1]);
        c2 = fminf(c2, sh.sFlat[w*4+2]); d2 = fmaxf(d2, sh.sFlat[w*4+3]);
      }
      mm_part[wg*4+0] = a; mm_part[wg*4+1] = b;
      mm_part[wg*4+2] = c2; mm_part[wg*4+3] = d2;
    }
  }
  grid.sync();
  if (tid == 0) {   // every WG redundantly reduces (identical result => uniform)
    float a = FBIG, b = -FBIG, c2 = FBIG, d2 = -FBIG;
    for (int w = 0; w < NWG; ++w) {
      a = fminf(a, mm_part[w*4+0]); b = fmaxf(b, mm_part[w*4+1]);
      c2 = fminf(c2, mm_part[w*4+2]); d2 = fmaxf(d2, mm_part[w*4+3]);
    }
    sh.sScal[0] = a; sh.sScal[1] = b; sh.sScal[2] = c2; sh.sScal[3] = d2;
  }
  __syncthreads();
  const float lo_p = sh.sScal[0], hi_p = sh.sScal[1];
  const float lo_n = sh.sScal[2], hi_n = sh.sScal[3];
  const float s_p = LAMf / (hi_p - lo_p);
  const float s_n = LAMf / (hi_n - lo_n);

  // ---- Sinkhorn iterations (both problems fused) ----
  bool done_p = false, done_n = false;
  for (int it = 0; it < NITERS; ++it) {
    sweep_pass<true >(sh, dist, targets, u_p, u_n, v_p, v_n,
                      s_p, s_n, lo_p, lo_n, !done_p, !done_n, err_part, wg, tid, lane, wv);
    grid.sync();
    sweep_pass<false>(sh, dist, targets, v_p, v_n, u_p, u_n,
                      s_p, s_n, lo_p, lo_n, !done_p, !done_n, err_part, wg, tid, lane, wv);
    grid.sync();
    {
      float ep = 0.0f, en = 0.0f;
      if (tid < NWG) { ep = err_part[2*tid]; en = err_part[2*tid+1]; }
      #pragma unroll
      for (int off = 32; off; off >>= 1) {
        ep += __shfl_xor(ep, off, 64);
        en += __shfl_xor(en, off, 64);
      }
      if (lane == 0) { sh.sFlat[wv*2] = ep; sh.sFlat[wv*2+1] = en; }
      __syncthreads();
      if (tid == 0) {
        float a = 0.0f, b = 0.0f;
        #pragma unroll
        for (int w = 0; w < NWAVE; ++w) { a += sh.sFlat[w*2]; b += sh.sFlat[w*2+1]; }
        sh.sScal[4] = a; sh.sScal[5] = b;
      }
      __syncthreads();
      if (sh.sScal[4] < THRESHf) done_p = true;
      if (sh.sScal[5] < THRESHf) done_n = true;
    }
    if (done_p && done_n) break;
  }

  // ---- loss = sum(pi_pos*edge_pos) + sum(pi_neg*edge_neg) ----
  __syncthreads();
  #pragma unroll
  for (int c = 0; c < NN / TPB; ++c) {
    const int j = tid + TPB * c;
    sh.sBpn[j] = make_float2(LAMf * v_p[j], LAMf * v_n[j]);
  }
  __syncthreads();
  {
    const int i = wg * RPW + wv;
    const int ti = targets[i];
    const float Ap = LAMf * u_p[i] + s_p * lo_p;
    const float An = LAMf * u_n[i] + s_n * lo_n;
    const unsigned short* drow = dist + (size_t)i * NN;
    float lacc = 0.0f;
    #pragma unroll 2
    for (int c = 0; c < 8; ++c) {
      const int j0 = lane * 8 + 512 * c;
      const uint4 dv = *(const uint4*)(drow + j0);
      const int4 t0 = *(const int4*)(sh.sT + j0);
      const int4 t1 = *(const int4*)(sh.sT + j0 + 4);
      const float4 q0 = *(const float4*)(&sh.sBpn[j0]);
      const float4 q1 = *(const float4*)(&sh.sBpn[j0 + 2]);
      const float4 q2 = *(const float4*)(&sh.sBpn[j0 + 4]);
      const float4 q3 = *(const float4*)(&sh.sBpn[j0 + 6]);
      float d8[8]; unp8(dv, d8);
      const int tt[8] = {t0.x, t0.y, t0.z, t0.w, t1.x, t1.y, t1.z, t1.w};
      const float bp[8] = {q0.x, q0.z, q1.x, q1.z, q2.x, q2.z, q3.x, q3.z};
      const float bn[8] = {q0.y, q0.w, q1.y, q1.w, q2.y, q2.w, q3.y, q3.w};
      #pragma unroll
      for (int q = 0; q < 8; ++q) {
        const bool pos = (tt[q] == ti);
        const float d = d8[q];
        const float crp = d + (d > 0.8f ? 1.0f : 0.0f);
        const float crn = (d < 0.4f ? 2.0f : 1.0f) - d;
        const float cr = pos ? crp : crn;
        const float A = pos ? Ap : An;
        const float B = pos ? bp[q] : bn[q];
        const float ss = pos ? s_p : s_n;
        const float pi = __expf(A + B - ss * cr);
        const float edge = pos ? fmaxf(0.8f - d, 0.0f) : fmaxf(d - 0.4f, 0.0f);
        lacc += pi * edge;   // cross-class terms ~1e-34 absolute: negligible, skipped
      }
    }
    #pragma unroll
    for (int off = 32; off; off >>= 1) lacc += __shfl_xor(lacc, off, 64);
    if (lane == 0) sh.sFlat[wv] = lacc;
    __syncthreads();
    if (tid == 0) {
      float s = 0.0f;
      #pragma unroll
      for (int w = 0; w < NWAVE; ++w) s += sh.sFlat[w];
      loss_part[wg] = s;
    }
  }
  grid.sync();
  if (wg == 0 && tid == 0) {
    float s = 0.0f;
    for (int w = 0; w < NWG; ++w) s += loss_part[w];
    out[0] = s;   // SCALE = 1.0
  }
}

// ---- fused row-norm + cast: ebf[i][k] = bf16(E[i][k] / max(||E_i||,1e-12)) ----
__global__ void __launch_bounds__(256) normcast_k(const float* __restrict__ E,
                                                  unsigned short* __restrict__ ebf)
{
  __shared__ float red[4];
  __shared__ float sinv;
  const int i = blockIdx.x;
  const int tid = threadIdx.x;
  const float4 v4 = ((const float4*)(E + (size_t)i * KK))[tid];
  float s = v4.x*v4.x + v4.y*v4.y + v4.z*v4.z + v4.w*v4.w;
  #pragma unroll
  for (int off = 32; off; off >>= 1) s += __shfl_xor(s, off, 64);
  if ((tid & 63) == 0) red[tid >> 6] = s;
  __syncthreads();
  if (tid == 0)
    sinv = 1.0f / fmaxf(sqrtf(red[0] + red[1] + red[2] + red[3]), 1e-12f);
  __syncthreads();
  const float iv = sinv;
  ushort4 o;
  o.x = f2bf(v4.x * iv); o.y = f2bf(v4.y * iv);
  o.z = f2bf(v4.z * iv); o.w = f2bf(v4.w * iv);
  ((ushort4*)(ebf + (size_t)i * KK))[tid] = o;
}

// ---- dist = Ehat @ Ehat^T via bf16 MFMA (m97-style 128x128 tile, BK=32) ----
#define GBM 128
#define GBK 32
__global__ void __launch_bounds__(256) gemm_bf16_k(const unsigned short* __restrict__ ebf,
                                                   unsigned short* __restrict__ dist)
{
  __shared__ unsigned short sA[GBM * GBK];   // 8 KB, linear (gload_lds dest)
  __shared__ unsigned short sB[GBM * GBK];   // 8 KB
  const int tid = threadIdx.x;
  const int lane = tid & 63;
  const int w = tid >> 6;
  const int wr = w >> 1, wc = w & 1;          // 2x2 wave grid, 64x64 per wave
  const int row0 = blockIdx.y * GBM;
  const int col0 = blockIdx.x * GBM;

  f32x4 acc[4][4];
  #pragma unroll
  for (int m = 0; m < 4; ++m)
    #pragma unroll
    for (int n = 0; n < 4; ++n) acc[m][n] = (f32x4){0.f, 0.f, 0.f, 0.f};

  for (int k0 = 0; k0 < KK; k0 += GBK) {
    #pragma unroll
    for (int q = 0; q < 2; ++q) {
      const int s = w * 2 + q;                 // segment 0..7: 16 rows each
      const int r = s * 16 + (lane >> 2);      // 4 lanes per 64B row
      const int jc = lane & 3;                 // 16B chunk within row
      const unsigned short* ga = ebf + (size_t)(row0 + r) * KK + k0 + jc * 8;
      const unsigned short* gb = ebf + (size_t)(col0 + r) * KK + k0 + jc * 8;
      __builtin_amdgcn_global_load_lds((const __attribute__((address_space(1))) void*)ga,
                                       (__attribute__((address_space(3))) void*)(sA + s * 512),
                                       16, 0, 0);
      __builtin_amdgcn_global_load_lds((const __attribute__((address_space(1))) void*)gb,
                                       (__attribute__((address_space(3))) void*)(sB + s * 512),
                                       16, 0, 0);
    }
    __syncthreads();
    const int rr = lane & 15;
    const int kc = lane >> 4;                  // k-group of 8
    bf16x8 af[4], bb[4];
    #pragma unroll
    for (int m = 0; m < 4; ++m)
      af[m] = *(const bf16x8*)&sA[(wr * 64 + m * 16 + rr) * GBK + kc * 8];
    #pragma unroll
    for (int n = 0; n < 4; ++n)
      bb[n] = *(const bf16x8*)&sB[(wc * 64 + n * 16 + rr) * GBK + kc * 8];
    #pragma unroll
    for (int m = 0; m < 4; ++m)
      #pragma unroll
      for (int n = 0; n < 4; ++n)
        acc[m][n] = __builtin_amdgcn_mfma_f32_16x16x32_bf16(af[m], bb[n], acc[m][n], 0, 0, 0);
    __syncthreads();
  }

  // C/D layout: col = lane&15, row = (lane>>4)*4 + reg  [m89-verified]
  #pragma unroll
  for (int m = 0; m < 4; ++m) {
    const int rb = row0 + wr * 64 + m * 16 + (lane >> 4) * 4;
    #pragma unroll
    for (int n = 0; n < 4; ++n) {
      const int cc = col0 + wc * 64 + n * 16 + (lane & 15);
      #pragma unroll
      for (int r = 0; r < 4; ++r)
        dist[(size_t)(rb + r) * NN + cc] = f2bf(acc[m][n][r]);
    }
  }
}

extern "C" void kernel_launch(void* const* d_in, const int* in_sizes, int n_in,
                              void* d_out, int out_size, void* d_ws, size_t ws_size,
                              hipStream_t stream) {
  (void)in_sizes; (void)n_in; (void)out_size; (void)ws_size;
  const float* E = (const float*)d_in[0];
  const int* T = (const int*)d_in[1];
  float* out = (float*)d_out;

  unsigned short* ebf  = (unsigned short*)d_ws;             // 4096*1024 bf16 = 8 MB
  unsigned short* dist = ebf + (size_t)NN * KK;             // 4096*4096 bf16 = 32 MB
  float* fbase = (float*)(dist + (size_t)NN * NN);          // 40 MB offset
  float* u_p       = fbase;
  float* u_n       = u_p + NN;
  float* v_p       = u_n + NN;
  float* v_n       = v_p + NN;
  float* mm_part   = v_n + NN;                              // NWG*4
  float* err_part  = mm_part + NWG * 4;                     // NWG*2
  float* loss_part = err_part + NWG * 2;                    // NWG

  normcast_k<<<NN, 256, 0, stream>>>(E, ebf);
  dim3 g(NN / GBM, NN / GBM);
  gemm_bf16_k<<<g, 256, 0, stream>>>(ebf, dist);

  void* args[] = { (void*)&dist, (void*)&T, (void*)&u_p, (void*)&u_n,
                   (void*)&v_p, (void*)&v_n, (void*)&mm_part,
                   (void*)&err_part, (void*)&loss_part, (void*)&out };
  hipLaunchCooperativeKernel(sinkhorn_all, dim3(NWG), dim3(TPB), args, 0u, stream);
}

// Round 13
// 378.156 us; speedup vs baseline: 2.1409x; 1.0673x over previous
//
#include <hip/hip_runtime.h>
#include <hip/hip_bf16.h>
#include <hip/hip_cooperative_groups.h>

namespace cg = cooperative_groups;

#define NN 4096
#define KK 1024
#define NWG 256
#define TPB 1024
#define NWAVE 16
#define RPW 16
#define LAMf 100.0f
#define LOGMU (-8.317766166719343f)
#define THRESHf 0.1f
#define NITERS 100
#define FBIG 3.402823466e+38f

typedef __attribute__((ext_vector_type(8))) short bf16x8;
typedef __attribute__((ext_vector_type(4))) float f32x4;

__device__ __forceinline__ float bflo(unsigned u) { return __uint_as_float(u << 16); }
__device__ __forceinline__ float bfhi(unsigned u) { return __uint_as_float(u & 0xffff0000u); }
__device__ __forceinline__ unsigned short f2bf(float x) {   // RNE f32->bf16 (finite inputs)
  unsigned u = __float_as_uint(x);
  return (unsigned short)((u + 0x7fffu + ((u >> 16) & 1u)) >> 16);
}

struct SweepShared {
  float sBp[NN];     // lam*other_p   16 KB  (separate arrays: float4 read at byte16*lane -> conflict-free)
  float sBn[NN];     // lam*other_n   16 KB
  int   sT[NN];      // targets       16 KB
  float sErr[2][RPW];
  float sFlat[64];
  float sScal[8];
};

// acc_all += e ; accp += pos?e:0   (accn derived as acc_all-accp by caller)
__device__ __forceinline__ void elem_accum(float d, int tj, int ti,
    float Bp, float Bn, float Ap, float An, float s_p, float s_n,
    float& acc_all, float& accp)
{
  const bool pos = (tj == ti);
  const float crp = d + (d > 0.8f ? 1.0f : 0.0f);          // pos raw cost
  const float crn = (d < 0.4f ? 2.0f : 1.0f) - d;          // neg raw cost
  const float cr = pos ? crp : crn;
  const float A  = pos ? Ap : An;
  const float B  = pos ? Bp : Bn;
  const float ss = pos ? s_p : s_n;
  const float e  = __expf(A + B - ss * cr);
  acc_all += e;
  accp += pos ? e : 0.0f;
}

// One half-iteration: LSE over rows of dist for "own" side, using staged "other" side.
// dist is symmetric, so both phases are row scans.
template<bool DO_ERR>
__device__ __forceinline__ void sweep_pass(
    SweepShared& sh,
    const unsigned short* __restrict__ dist, const int* __restrict__ targets,
    float* __restrict__ ownP, float* __restrict__ ownN,
    const float* __restrict__ othP, const float* __restrict__ othN,
    float s_p, float s_n, float lo_p, float lo_n,
    bool actP, bool actN, float* __restrict__ err_part,
    int wg, int tid, int lane, int wv)
{
  __syncthreads();
  {
    const float4 vp = *(const float4*)(othP + tid * 4);
    const float4 vn = *(const float4*)(othN + tid * 4);
    *(float4*)(sh.sBp + tid * 4) = make_float4(LAMf*vp.x, LAMf*vp.y, LAMf*vp.z, LAMf*vp.w);
    *(float4*)(sh.sBn + tid * 4) = make_float4(LAMf*vn.x, LAMf*vn.y, LAMf*vn.z, LAMf*vn.w);
  }
  __syncthreads();

  const int i = wg * RPW + wv;          // this wave's row (== col, dist symmetric)
  const int ti = targets[i];
  const float uop = ownP[i];
  const float uon = ownN[i];
  const float Ap = LAMf * uop + s_p * lo_p;
  const float An = LAMf * uon + s_n * lo_n;
  const unsigned short* __restrict__ drow = dist + (size_t)i * NN;
  float acc_all = 0.0f, accp = 0.0f;
  #pragma unroll 4
  for (int c = 0; c < 16; ++c) {
    const int j0 = lane * 4 + 256 * c;
    const uint2 dv = *(const uint2*)(drow + j0);
    const int4 t4 = *(const int4*)(sh.sT + j0);
    const float4 bp4 = *(const float4*)(sh.sBp + j0);
    const float4 bn4 = *(const float4*)(sh.sBn + j0);
    elem_accum(bflo(dv.x), t4.x, ti, bp4.x, bn4.x, Ap, An, s_p, s_n, acc_all, accp);
    elem_accum(bfhi(dv.x), t4.y, ti, bp4.y, bn4.y, Ap, An, s_p, s_n, acc_all, accp);
    elem_accum(bflo(dv.y), t4.z, ti, bp4.z, bn4.z, Ap, An, s_p, s_n, acc_all, accp);
    elem_accum(bfhi(dv.y), t4.w, ti, bp4.w, bn4.w, Ap, An, s_p, s_n, acc_all, accp);
  }
  float accn = acc_all - accp;
  #pragma unroll
  for (int off = 32; off; off >>= 1) {
    accp += __shfl_xor(accp, off, 64);
    accn += __shfl_xor(accn, off, 64);
  }
  if (lane == 0) {
    const float unp = (LOGMU - logf(accp + 1e-6f)) / LAMf + uop;
    const float unn = (LOGMU - logf(accn + 1e-6f)) / LAMf + uon;
    if (actP) ownP[i] = unp;
    if (actN) ownN[i] = unn;
    if (DO_ERR) {
      sh.sErr[0][wv] = fabsf(unp - uop);
      sh.sErr[1][wv] = fabsf(unn - uon);
    }
  }
  if (DO_ERR) {
    __syncthreads();
    if (tid < 2) {
      const bool act = tid ? actN : actP;
      if (act) {
        float e = 0.0f;
        #pragma unroll
        for (int r = 0; r < RPW; ++r) e += sh.sErr[tid][r];
        err_part[wg * 2 + tid] = e;
      }
    }
  }
}

__global__ void __launch_bounds__(TPB, 1) sinkhorn_all(
    const unsigned short* __restrict__ dist, const int* __restrict__ targets,
    float* __restrict__ u_p, float* __restrict__ u_n,
    float* __restrict__ v_p, float* __restrict__ v_n,
    float* __restrict__ mm_part, float* __restrict__ err_part,
    float* __restrict__ loss_part, float* __restrict__ out)
{
  cg::grid_group grid = cg::this_grid();
  __shared__ SweepShared sh;
  const int tid = threadIdx.x;
  const int wg = blockIdx.x;
  const int lane = tid & 63;
  const int wv = tid >> 6;

  #pragma unroll
  for (int c = 0; c < NN / TPB; ++c) {
    const int j = tid + TPB * c;
    sh.sT[j] = targets[j];
  }
  if (tid < RPW) {
    const int i = wg * RPW + tid;
    u_p[i] = 0.0f; u_n[i] = 0.0f; v_p[i] = 0.0f; v_n[i] = 0.0f;
  }
  __syncthreads();

  // ---- global min/max of raw cost matrices (for _minmax_norm constants) ----
  {
    const int i = wg * RPW + wv;
    const int ti = targets[i];
    const unsigned short* drow = dist + (size_t)i * NN;
    float mnp = FBIG, mxp = -FBIG, mnn = FBIG, mxn = -FBIG;
    #pragma unroll 4
    for (int c = 0; c < 16; ++c) {
      const int j0 = lane * 4 + 256 * c;
      const uint2 dv = *(const uint2*)(drow + j0);
      const int4 t4 = *(const int4*)(sh.sT + j0);
      const float d4[4] = {bflo(dv.x), bfhi(dv.x), bflo(dv.y), bfhi(dv.y)};
      const int tt[4] = {t4.x, t4.y, t4.z, t4.w};
      #pragma unroll
      for (int q = 0; q < 4; ++q) {
        const bool pos = (tt[q] == ti);
        const float d = d4[q];
        const float crp = pos ? (d + (d > 0.8f ? 1.0f : 0.0f)) : 30.0f;
        const float crn = pos ? 30.0f : ((d < 0.4f ? 2.0f : 1.0f) - d);
        mnp = fminf(mnp, crp); mxp = fmaxf(mxp, crp);
        mnn = fminf(mnn, crn); mxn = fmaxf(mxn, crn);
      }
    }
    #pragma unroll
    for (int off = 32; off; off >>= 1) {
      mnp = fminf(mnp, __shfl_xor(mnp, off, 64));
      mxp = fmaxf(mxp, __shfl_xor(mxp, off, 64));
      mnn = fminf(mnn, __shfl_xor(mnn, off, 64));
      mxn = fmaxf(mxn, __shfl_xor(mxn, off, 64));
    }
    if (lane == 0) {
      sh.sFlat[wv * 4 + 0] = mnp; sh.sFlat[wv * 4 + 1] = mxp;
      sh.sFlat[wv * 4 + 2] = mnn; sh.sFlat[wv * 4 + 3] = mxn;
    }
    __syncthreads();
    if (tid == 0) {
      float a = FBIG, b = -FBIG, c2 = FBIG, d2 = -FBIG;
      #pragma unroll
      for (int w = 0; w < NWAVE; ++w) {
        a = fminf(a, sh.sFlat[w*4+0]); b = fmaxf(b, sh.sFlat[w*4+1]);
        c2 = fminf(c2, sh.sFlat[w*4+2]); d2 = fmaxf(d2, sh.sFlat[w*4+3]);
      }
      mm_part[wg*4+0] = a; mm_part[wg*4+1] = b;
      mm_part[wg*4+2] = c2; mm_part[wg*4+3] = d2;
    }
  }
  grid.sync();
  if (tid == 0) {   // every WG redundantly reduces (identical result => uniform)
    float a = FBIG, b = -FBIG, c2 = FBIG, d2 = -FBIG;
    for (int w = 0; w < NWG; ++w) {
      a = fminf(a, mm_part[w*4+0]); b = fmaxf(b, mm_part[w*4+1]);
      c2 = fminf(c2, mm_part[w*4+2]); d2 = fmaxf(d2, mm_part[w*4+3]);
    }
    sh.sScal[0] = a; sh.sScal[1] = b; sh.sScal[2] = c2; sh.sScal[3] = d2;
  }
  __syncthreads();
  const float lo_p = sh.sScal[0], hi_p = sh.sScal[1];
  const float lo_n = sh.sScal[2], hi_n = sh.sScal[3];
  const float s_p = LAMf / (hi_p - lo_p);
  const float s_n = LAMf / (hi_n - lo_n);

  // ---- Sinkhorn iterations (both problems fused) ----
  bool done_p = false, done_n = false;
  for (int it = 0; it < NITERS; ++it) {
    sweep_pass<true >(sh, dist, targets, u_p, u_n, v_p, v_n,
                      s_p, s_n, lo_p, lo_n, !done_p, !done_n, err_part, wg, tid, lane, wv);
    grid.sync();
    sweep_pass<false>(sh, dist, targets, v_p, v_n, u_p, u_n,
                      s_p, s_n, lo_p, lo_n, !done_p, !done_n, err_part, wg, tid, lane, wv);
    grid.sync();
    {
      float ep = 0.0f, en = 0.0f;
      if (tid < NWG) { ep = err_part[2*tid]; en = err_part[2*tid+1]; }
      #pragma unroll
      for (int off = 32; off; off >>= 1) {
        ep += __shfl_xor(ep, off, 64);
        en += __shfl_xor(en, off, 64);
      }
      if (lane == 0) { sh.sFlat[wv*2] = ep; sh.sFlat[wv*2+1] = en; }
      __syncthreads();
      if (tid == 0) {
        float a = 0.0f, b = 0.0f;
        #pragma unroll
        for (int w = 0; w < NWAVE; ++w) { a += sh.sFlat[w*2]; b += sh.sFlat[w*2+1]; }
        sh.sScal[4] = a; sh.sScal[5] = b;
      }
      __syncthreads();
      if (sh.sScal[4] < THRESHf) done_p = true;
      if (sh.sScal[5] < THRESHf) done_n = true;
    }
    if (done_p && done_n) break;
  }

  // ---- loss = sum(pi_pos*edge_pos) + sum(pi_neg*edge_neg) ----
  __syncthreads();
  {
    const float4 vp = *(const float4*)(v_p + tid * 4);
    const float4 vn = *(const float4*)(v_n + tid * 4);
    *(float4*)(sh.sBp + tid * 4) = make_float4(LAMf*vp.x, LAMf*vp.y, LAMf*vp.z, LAMf*vp.w);
    *(float4*)(sh.sBn + tid * 4) = make_float4(LAMf*vn.x, LAMf*vn.y, LAMf*vn.z, LAMf*vn.w);
  }
  __syncthreads();
  {
    const int i = wg * RPW + wv;
    const int ti = targets[i];
    const float Ap = LAMf * u_p[i] + s_p * lo_p;
    const float An = LAMf * u_n[i] + s_n * lo_n;
    const unsigned short* drow = dist + (size_t)i * NN;
    float lacc = 0.0f;
    #pragma unroll 4
    for (int c = 0; c < 16; ++c) {
      const int j0 = lane * 4 + 256 * c;
      const uint2 dv = *(const uint2*)(drow + j0);
      const int4 t4 = *(const int4*)(sh.sT + j0);
      const float4 bp4 = *(const float4*)(sh.sBp + j0);
      const float4 bn4 = *(const float4*)(sh.sBn + j0);
      const float d4[4] = {bflo(dv.x), bfhi(dv.x), bflo(dv.y), bfhi(dv.y)};
      const int tt[4] = {t4.x, t4.y, t4.z, t4.w};
      const float bp[4] = {bp4.x, bp4.y, bp4.z, bp4.w};
      const float bn[4] = {bn4.x, bn4.y, bn4.z, bn4.w};
      #pragma unroll
      for (int q = 0; q < 4; ++q) {
        const bool pos = (tt[q] == ti);
        const float d = d4[q];
        const float crp = d + (d > 0.8f ? 1.0f : 0.0f);
        const float crn = (d < 0.4f ? 2.0f : 1.0f) - d;
        const float cr = pos ? crp : crn;
        const float A = pos ? Ap : An;
        const float B = pos ? bp[q] : bn[q];
        const float ss = pos ? s_p : s_n;
        const float pi = __expf(A + B - ss * cr);
        const float edge = pos ? fmaxf(0.8f - d, 0.0f) : fmaxf(d - 0.4f, 0.0f);
        lacc += pi * edge;   // cross-class terms ~1e-34 absolute: negligible, skipped
      }
    }
    #pragma unroll
    for (int off = 32; off; off >>= 1) lacc += __shfl_xor(lacc, off, 64);
    if (lane == 0) sh.sFlat[wv] = lacc;
    __syncthreads();
    if (tid == 0) {
      float s = 0.0f;
      #pragma unroll
      for (int w = 0; w < NWAVE; ++w) s += sh.sFlat[w];
      loss_part[wg] = s;
    }
  }
  grid.sync();
  if (wg == 0 && tid == 0) {
    float s = 0.0f;
    for (int w = 0; w < NWG; ++w) s += loss_part[w];
    out[0] = s;   // SCALE = 1.0
  }
}

// ---- fused row-norm + cast: ebf[i][k] = bf16(E[i][k] / max(||E_i||,1e-12)) ----
__global__ void __launch_bounds__(256) normcast_k(const float* __restrict__ E,
                                                  unsigned short* __restrict__ ebf)
{
  __shared__ float red[4];
  __shared__ float sinv;
  const int i = blockIdx.x;
  const int tid = threadIdx.x;
  const float4 v4 = ((const float4*)(E + (size_t)i * KK))[tid];
  float s = v4.x*v4.x + v4.y*v4.y + v4.z*v4.z + v4.w*v4.w;
  #pragma unroll
  for (int off = 32; off; off >>= 1) s += __shfl_xor(s, off, 64);
  if ((tid & 63) == 0) red[tid >> 6] = s;
  __syncthreads();
  if (tid == 0)
    sinv = 1.0f / fmaxf(sqrtf(red[0] + red[1] + red[2] + red[3]), 1e-12f);
  __syncthreads();
  const float iv = sinv;
  ushort4 o;
  o.x = f2bf(v4.x * iv); o.y = f2bf(v4.y * iv);
  o.z = f2bf(v4.z * iv); o.w = f2bf(v4.w * iv);
  ((ushort4*)(ebf + (size_t)i * KK))[tid] = o;
}

// ---- dist = Ehat @ Ehat^T via bf16 MFMA (m97-style 128x128 tile, BK=32) ----
#define GBM 128
#define GBK 32
__global__ void __launch_bounds__(256) gemm_bf16_k(const unsigned short* __restrict__ ebf,
                                                   unsigned short* __restrict__ dist)
{
  __shared__ unsigned short sA[GBM * GBK];   // 8 KB, linear (gload_lds dest)
  __shared__ unsigned short sB[GBM * GBK];   // 8 KB
  const int tid = threadIdx.x;
  const int lane = tid & 63;
  const int w = tid >> 6;
  const int wr = w >> 1, wc = w & 1;          // 2x2 wave grid, 64x64 per wave
  const int row0 = blockIdx.y * GBM;
  const int col0 = blockIdx.x * GBM;

  f32x4 acc[4][4];
  #pragma unroll
  for (int m = 0; m < 4; ++m)
    #pragma unroll
    for (int n = 0; n < 4; ++n) acc[m][n] = (f32x4){0.f, 0.f, 0.f, 0.f};

  for (int k0 = 0; k0 < KK; k0 += GBK) {
    #pragma unroll
    for (int q = 0; q < 2; ++q) {
      const int s = w * 2 + q;                 // segment 0..7: 16 rows each
      const int r = s * 16 + (lane >> 2);      // 4 lanes per 64B row
      const int jc = lane & 3;                 // 16B chunk within row
      const unsigned short* ga = ebf + (size_t)(row0 + r) * KK + k0 + jc * 8;
      const unsigned short* gb = ebf + (size_t)(col0 + r) * KK + k0 + jc * 8;
      __builtin_amdgcn_global_load_lds((const __attribute__((address_space(1))) void*)ga,
                                       (__attribute__((address_space(3))) void*)(sA + s * 512),
                                       16, 0, 0);
      __builtin_amdgcn_global_load_lds((const __attribute__((address_space(1))) void*)gb,
                                       (__attribute__((address_space(3))) void*)(sB + s * 512),
                                       16, 0, 0);
    }
    __syncthreads();
    const int rr = lane & 15;
    const int kc = lane >> 4;                  // k-group of 8
    bf16x8 af[4], bb[4];
    #pragma unroll
    for (int m = 0; m < 4; ++m)
      af[m] = *(const bf16x8*)&sA[(wr * 64 + m * 16 + rr) * GBK + kc * 8];
    #pragma unroll
    for (int n = 0; n < 4; ++n)
      bb[n] = *(const bf16x8*)&sB[(wc * 64 + n * 16 + rr) * GBK + kc * 8];
    #pragma unroll
    for (int m = 0; m < 4; ++m)
      #pragma unroll
      for (int n = 0; n < 4; ++n)
        acc[m][n] = __builtin_amdgcn_mfma_f32_16x16x32_bf16(af[m], bb[n], acc[m][n], 0, 0, 0);
    __syncthreads();
  }

  // C/D layout: col = lane&15, row = (lane>>4)*4 + reg  [m89-verified]
  #pragma unroll
  for (int m = 0; m < 4; ++m) {
    const int rb = row0 + wr * 64 + m * 16 + (lane >> 4) * 4;
    #pragma unroll
    for (int n = 0; n < 4; ++n) {
      const int cc = col0 + wc * 64 + n * 16 + (lane & 15);
      #pragma unroll
      for (int r = 0; r < 4; ++r)
        dist[(size_t)(rb + r) * NN + cc] = f2bf(acc[m][n][r]);
    }
  }
}

extern "C" void kernel_launch(void* const* d_in, const int* in_sizes, int n_in,
                              void* d_out, int out_size, void* d_ws, size_t ws_size,
                              hipStream_t stream) {
  (void)in_sizes; (void)n_in; (void)out_size; (void)ws_size;
  const float* E = (const float*)d_in[0];
  const int* T = (const int*)d_in[1];
  float* out = (float*)d_out;

  unsigned short* ebf  = (unsigned short*)d_ws;             // 4096*1024 bf16 = 8 MB
  unsigned short* dist = ebf + (size_t)NN * KK;             // 4096*4096 bf16 = 32 MB
  float* fbase = (float*)(dist + (size_t)NN * NN);          // 40 MB offset
  float* u_p       = fbase;
  float* u_n       = u_p + NN;
  float* v_p       = u_n + NN;
  float* v_n       = v_p + NN;
  float* mm_part   = v_n + NN;                              // NWG*4
  float* err_part  = mm_part + NWG * 4;                     // NWG*2
  float* loss_part = err_part + NWG * 2;                    // NWG

  normcast_k<<<NN, 256, 0, stream>>>(E, ebf);
  dim3 g(NN / GBM, NN / GBM);
  gemm_bf16_k<<<g, 256, 0, stream>>>(ebf, dist);

  void* args[] = { (void*)&dist, (void*)&T, (void*)&u_p, (void*)&u_n,
                   (void*)&v_p, (void*)&v_n, (void*)&mm_part,
                   (void*)&err_part, (void*)&loss_part, (void*)&out };
  hipLaunchCooperativeKernel(sinkhorn_all, dim3(NWG), dim3(TPB), args, 0u, stream);
}